// Round 11
// baseline (319.393 us; speedup 1.0000x reference)
//
#include <hip/hip_runtime.h>
#include <hip/hip_bf16.h>
#include <stdint.h>

typedef __hip_bfloat16 bf16;
typedef __attribute__((ext_vector_type(8))) short short8;
typedef __attribute__((ext_vector_type(4))) float f32x4;

#define NEG 0.2f
#define LN_EPS 1e-5f

// Channel permutation (per 64-block): slot = 64a + 4*l + c  <->  std = 64a + 16c + l
__device__ __host__ __forceinline__ int stdch(int q) {
    return (q & ~63) | (16 * (q & 3)) | ((q & 63) >> 2);
}

__device__ __forceinline__ float bits2f(unsigned b) {  // low 16 bits = bf16
    return __uint_as_float(b << 16);
}
__device__ __forceinline__ float hi2f(unsigned b) {    // high 16 bits = bf16
    return __uint_as_float(b & 0xffff0000u);
}
__device__ __forceinline__ unsigned short f2b_bits(float f) {  // RNE f32->bf16 bits
    unsigned u = __float_as_uint(f);
    unsigned r = u + 0x7fffu + ((u >> 16) & 1u);
    return (unsigned short)(r >> 16);
}
__device__ __forceinline__ float lrelu(float v) {
    return fmaxf(v, 0.f) + NEG * fminf(v, 0.f);
}
__device__ __forceinline__ void unpack8(uint4 u, float* v) {
    v[0] = bits2f(u.x); v[1] = hi2f(u.x);
    v[2] = bits2f(u.y); v[3] = hi2f(u.y);
    v[4] = bits2f(u.z); v[5] = hi2f(u.z);
    v[6] = bits2f(u.w); v[7] = hi2f(u.w);
}
__device__ __forceinline__ float ub2f(unsigned d, int b) {  // byte b of dword -> float
    return (float)((d >> (8 * b)) & 0xffu);                 // ISel: v_cvt_f32_ubyteN
}

union S8 { uint4 u; short8 s; unsigned short us[8]; };
__device__ __forceinline__ short8 ld8b(const char* p) {
    S8 c; c.u = *(const uint4*)p; return c.s;
}
__device__ __forceinline__ short8 ld8f(const float* p) {
    float4 a = ((const float4*)p)[0], b = ((const float4*)p)[1];
    S8 c;
    c.us[0] = f2b_bits(a.x); c.us[1] = f2b_bits(a.y);
    c.us[2] = f2b_bits(a.z); c.us[3] = f2b_bits(a.w);
    c.us[4] = f2b_bits(b.x); c.us[5] = f2b_bits(b.y);
    c.us[6] = f2b_bits(b.z); c.us[7] = f2b_bits(b.w);
    return c.s;
}

// All-lanes reduce within each 16-lane row via DPP row_ror rotation
template <int CTRL>
__device__ __forceinline__ float ror_add16(float x) {
    int xi = __float_as_int(x);
    int r = __builtin_amdgcn_update_dpp(xi, xi, CTRL, 0xf, 0xf, false);
    return x + __int_as_float(r);
}
template <int CTRL>
__device__ __forceinline__ float ror_max16(float x) {
    int xi = __float_as_int(x);
    int r = __builtin_amdgcn_update_dpp(xi, xi, CTRL, 0xf, 0xf, false);
    return fmaxf(x, __int_as_float(r));
}

// ---- K0: detect float dtype (flags[0]=1 -> bf16) and index width (flags[1]=1 -> int64)
__global__ void detect_kernel(const unsigned* __restrict__ xw, const int* __restrict__ ei,
                              int* __restrict__ flags, int E) {
    int lane = threadIdx.x;  // 64 threads
    int sane = 0;
    for (int k = 0; k < 4; ++k) {
        unsigned short lo = (unsigned short)(xw[k * 64 + lane] & 0xFFFFu);
        int ex = (lo >> 7) & 0xFF;
        if (lo == 0 || (ex > 100 && ex < 155)) sane++;
    }
#pragma unroll
    for (int off = 32; off > 0; off >>= 1) sane += __shfl_xor(sane, off);
    int nchk = E < 64 ? E : 64;
    int bad = (lane < nchk) ? (ei[2 * lane + 1] != 0) : 0;
    unsigned long long bb = __ballot(bad);
    if (lane == 0) {
        flags[0] = (sane > 200) ? 1 : 0;
        flags[1] = (bb == 0ULL) ? 1 : 0;
    }
}

// ---- K1: prep: fragment-ordered weight tables (1 KB contiguous per B-load),
//          small cvt, edge histogram.
// Layout: W[(nb*K4 + k4)*64 + lane]*8 + j  where col = nb*16+(lane&15),
//         k = k4*32+(lane>>4)*8+j.  K4 = K/32.
struct PrepArgs {
    const void* Wl; const void* Wr; const void* W1; const void* W2;
    const void* ssrc[8];   // b_l, b_r, att, gat_bias, ln_g, ln_b, b1, b2
    const int* ei;
    unsigned short* Wlt; unsigned short* Wrt; unsigned short* W1t; unsigned short* W2x;
    float* smalls;         // 2304 floats
    int* deg;
    int N; int E;
};
__device__ __forceinline__ float cvt_one(const void* p, int idx, int isb) {
    return isb ? bits2f(((const unsigned short*)p)[idx]) : ((const float*)p)[idx];
}
__global__ __launch_bounds__(256) void prep_kernel(PrepArgs a, const int* __restrict__ flags) {
    int isb = flags[0];
    int i = blockIdx.x * 256 + threadIdx.x;
    int seg = blockIdx.y;
    if (seg == 0) {         // Wlt frag-order (512 cols, K=128, K4=4, nb 0..31)
        if (i < 512 * 128) {
            int j = i & 7, lane = (i >> 3) & 63, k4 = (i >> 9) & 3, nb = i >> 11;
            int col = nb * 16 + (lane & 15);
            int k = k4 * 32 + (lane >> 4) * 8 + j;
            a.Wlt[i] = isb ? ((const unsigned short*)a.Wl)[k * 512 + col]
                           : f2b_bits(((const float*)a.Wl)[k * 512 + col]);
        }
    } else if (seg == 1) {  // Wrt frag-order
        if (i < 512 * 128) {
            int j = i & 7, lane = (i >> 3) & 63, k4 = (i >> 9) & 3, nb = i >> 11;
            int col = nb * 16 + (lane & 15);
            int k = k4 * 32 + (lane >> 4) * 8 + j;
            a.Wrt[i] = isb ? ((const unsigned short*)a.Wr)[k * 512 + col]
                           : f2b_bits(((const float*)a.Wr)[k * 512 + col]);
        }
    } else if (seg == 2) {  // W1t frag-order (256 cols, K=128 in hn slot order, nb 0..15)
        if (i < 256 * 128) {
            int j = i & 7, lane = (i >> 3) & 63;
            int r2 = i >> 9;          // 0..63
            int k4 = r2 & 3, nb = r2 >> 2;
            int col = nb * 16 + (lane & 15);
            int q = k4 * 32 + (lane >> 4) * 8 + j;   // slot-k
            int k = stdch(q);
            a.W1t[i] = isb ? ((const unsigned short*)a.W1)[k * 256 + col]
                           : f2b_bits(((const float*)a.W1)[k * 256 + col]);
        }
    } else if (seg == 3) {  // W2x frag-order (128 cols, K=384: 256 W2 + 128 perm-identity)
        if (i < 128 * 384) {
            int j = i & 7, lane = (i >> 3) & 63;
            int r2 = i >> 9;          // 0..95
            int k4 = r2 % 12, nb = r2 / 12;
            int col = nb * 16 + (lane & 15);
            int p = k4 * 32 + (lane >> 4) * 8 + j;   // 0..383
            if (p < 256) {
                int k = stdch(p);
                a.W2x[i] = isb ? ((const unsigned short*)a.W2)[k * 128 + col]
                               : f2b_bits(((const float*)a.W2)[k * 128 + col]);
            } else {
                int q = p - 256;
                a.W2x[i] = (stdch(q) == col) ? (unsigned short)0x3F80 : (unsigned short)0;
            }
        }
    } else if (seg == 4) {  // edge histogram (deg pre-zeroed by hipMemsetAsync)
        if (i < a.E) {
            int d = flags[1] ? a.ei[2 * (size_t)a.E + 2 * (size_t)i] : a.ei[(size_t)a.E + i];
            if ((unsigned)d >= (unsigned)a.N) d = 0;
            atomicAdd(&a.deg[d], 1);
        }
    } else {                // smalls: b_l[0,512) b_r[512,1024) att_p[1024,1536)
                            //         gb_p[1536,1664) lng_p[1664,1792) lnb_p[1792,1920)
                            //         b1[1920,2176) b2[2176,2304)
        if (i < 512) a.smalls[i] = cvt_one(a.ssrc[0], i, isb);
        else if (i < 1024) a.smalls[i] = cvt_one(a.ssrc[1], i - 512, isb);
        else if (i < 1536) {
            int j = i - 1024, h = j >> 7, q = j & 127;
            a.smalls[i] = cvt_one(a.ssrc[2], h * 128 + stdch(q), isb);
        } else if (i < 1664) a.smalls[i] = cvt_one(a.ssrc[3], stdch(i - 1536), isb);
        else if (i < 1792)   a.smalls[i] = cvt_one(a.ssrc[4], stdch(i - 1664), isb);
        else if (i < 1920)   a.smalls[i] = cvt_one(a.ssrc[5], stdch(i - 1792), isb);
        else if (i < 2176)   a.smalls[i] = cvt_one(a.ssrc[6], i - 1920, isb);
        else if (i < 2304)   a.smalls[i] = cvt_one(a.ssrc[7], i - 2176, isb);
    }
}

// ================= MFMA GEMM =================
// A (16x32): lane holds A[m=lane&15][k=quad*8+j]; B (32x16): B[k=quad*8+j][n=lane&15]
// C/D: reg j -> row=quad*4+j, col=lane&15.  (m89/m91-verified)

// ---- K2: merged proj + scatter.
// R10 NEW: xl stored as int8 with per-(row, 64-slot-chunk) scale (scl[N][8] f32).
// agg's 471 MB logical gather was at ~95% of the 6.3 TB/s streaming ceiling --
// halving bytes is the only remaining lever. Scale is per wave-owned chunk:
// in-wave abs-max (3 max + 4 DPP-16), no cross-wave reduce. Quant err <= max/254
// (~0.4%) keeps absmax near the bf16 floor (unlike raw fp8's ~6%).
__global__ __launch_bounds__(256) void proj_scatter_kernel(
    const void* __restrict__ xv, const unsigned short* __restrict__ Wlt,
    const unsigned short* __restrict__ Wrt, const float* __restrict__ smalls,
    unsigned char* __restrict__ xl8, float* __restrict__ sclp,
    unsigned short* __restrict__ xr,
    const int* __restrict__ ei, int* __restrict__ cursor, int* __restrict__ srcs,
    int N, int E, int ET, int gproj, const int* __restrict__ flags) {
    if ((int)blockIdx.x >= gproj) {
        // ---- scatter tail blocks ----
        int e = ((int)blockIdx.x - gproj) * 256 + (int)threadIdx.x;
        if (e >= ET) return;
        int s, d;
        if (e < E) {
            if (flags[1]) { s = ei[2 * (size_t)e]; d = ei[2 * (size_t)E + 2 * (size_t)e]; }
            else          { s = ei[e];             d = ei[(size_t)E + e]; }
        } else { s = e - E; d = s; }
        if ((unsigned)s >= (unsigned)N) s = 0;
        if ((unsigned)d >= (unsigned)N) d = 0;
        int pos = atomicAdd(&cursor[d], 1);
        srcs[pos] = s;
        return;
    }
    // ---- proj body ----
    __shared__ __align__(16) unsigned short alds[64 * 136];  // 272-B row stride
    __shared__ float sclds[64 * 8];                          // per-(row,chunk) scales
    int isb = flags[0];
    int tt = (int)threadIdx.x;
    int wid = threadIdx.x >> 6, lane = threadIdx.x & 63;
    int quad = lane >> 4, l16 = lane & 15;
    int m0 = blockIdx.x * 64;

    // stage A (64 rows x 256 B bf16) into LDS, coalesced 16 B/thread
#pragma unroll
    for (int s = 0; s < 4; ++s) {
        int row = s * 16 + (tt >> 4);
        int gr = m0 + row; gr = (gr < N) ? gr : N - 1;
        S8 c8;
        if (isb) c8.u = *(const uint4*)((const char*)xv + (size_t)gr * 256 + (tt & 15) * 16);
        else     c8.s = ld8f((const float*)xv + (size_t)gr * 128 + (tt & 15) * 8);
        *(uint4*)(alds + row * 136 + (tt & 15) * 8) = c8.u;
    }
    __syncthreads();
    short8 A[4][4];
#pragma unroll
    for (int rf = 0; rf < 4; ++rf)
#pragma unroll
        for (int k4 = 0; k4 < 4; ++k4)
            A[rf][k4] = ld8b((const char*)(alds + (rf * 16 + l16) * 136 + k4 * 32 + quad * 8));

    for (int iter = 0; iter < 4; ++iter) {
        const unsigned short* Wt = (iter < 2) ? Wlt : Wrt;
        const float* bias = smalls + ((iter < 2) ? 0 : 512);
        int n0 = (iter & 1) * 256 + wid * 64;
        int nb0 = n0 >> 4;

        f32x4 acc[4][4];
#pragma unroll
        for (int rf = 0; rf < 4; ++rf)
#pragma unroll
            for (int c = 0; c < 4; ++c) acc[rf][c] = (f32x4){0.f, 0.f, 0.f, 0.f};

#pragma unroll
        for (int k4 = 0; k4 < 4; ++k4) {
            short8 b[4];
#pragma unroll
            for (int c = 0; c < 4; ++c)
                b[c] = ld8b((const char*)(Wt + (((size_t)(nb0 + c) * 4 + k4) * 64 + lane) * 8));
#pragma unroll
            for (int rf = 0; rf < 4; ++rf)
#pragma unroll
                for (int c = 0; c < 4; ++c)
                    acc[rf][c] = __builtin_amdgcn_mfma_f32_16x16x32_bf16(A[rf][k4], b[c], acc[rf][c], 0, 0, 0);
        }
        float bv[4];
#pragma unroll
        for (int c = 0; c < 4; ++c) bv[c] = bias[n0 + c * 16 + l16];
        if (iter < 2) {
            // ---- int8 quantized xl output (row = 512 B, slot s at byte s) ----
            int chunk = n0 >> 6;
#pragma unroll
            for (int rf = 0; rf < 4; ++rf) {
#pragma unroll
                for (int j = 0; j < 4; ++j) {
                    float a0 = acc[rf][0][j] + bv[0];
                    float a1 = acc[rf][1][j] + bv[1];
                    float a2 = acc[rf][2][j] + bv[2];
                    float a3 = acc[rf][3][j] + bv[3];
                    float lm = fmaxf(fmaxf(fabsf(a0), fabsf(a1)),
                                     fmaxf(fabsf(a2), fabsf(a3)));
                    lm = ror_max16<0x128>(lm);
                    lm = ror_max16<0x124>(lm);
                    lm = ror_max16<0x122>(lm);
                    lm = ror_max16<0x121>(lm);
                    float inv = (lm > 1e-20f) ? 127.f / lm : 0.f;
                    int lrow = rf * 16 + quad * 4 + j;
                    if (l16 == 0) sclds[lrow * 8 + chunk] = lm * (1.f / 127.f);
                    int q0 = (int)rintf(a0 * inv) + 128;
                    int q1 = (int)rintf(a1 * inv) + 128;
                    int q2 = (int)rintf(a2 * inv) + 128;
                    int q3 = (int)rintf(a3 * inv) + 128;
                    unsigned pk = (unsigned)q0 | ((unsigned)q1 << 8) |
                                  ((unsigned)q2 << 16) | ((unsigned)q3 << 24);
                    int row = m0 + lrow;
                    if (row < N)
                        *(unsigned*)(xl8 + (size_t)row * 512 + n0 + 4 * l16) = pk;
                }
            }
        } else {
            // ---- bf16 xr output (unchanged) ----
#pragma unroll
            for (int rf = 0; rf < 4; ++rf) {
#pragma unroll
                for (int j = 0; j < 4; ++j) {
                    int row = m0 + rf * 16 + quad * 4 + j;
                    if (row < N) {
                        uint2 pk;
                        pk.x = (unsigned)f2b_bits(acc[rf][0][j] + bv[0]) |
                               ((unsigned)f2b_bits(acc[rf][1][j] + bv[1]) << 16);
                        pk.y = (unsigned)f2b_bits(acc[rf][2][j] + bv[2]) |
                               ((unsigned)f2b_bits(acc[rf][3][j] + bv[3]) << 16);
                        *(uint2*)(xr + (size_t)row * 512 + n0 + 4 * l16) = pk;
                    }
                }
            }
        }
    }
    // ---- coalesced scale write (512 floats) ----
    __syncthreads();
#pragma unroll
    for (int k = 0; k < 2; ++k) {
        int idx = k * 256 + tt;
        int lrow = idx >> 3;
        if (m0 + lrow < N) sclp[(size_t)(m0 + lrow) * 8 + (idx & 7)] = sclds[idx];
    }
}

// ---- CSR build (deg holds edge-count only; +1 self-loop folded into scans) ----
__global__ __launch_bounds__(256) void scanA_kernel(const int* __restrict__ deg,
                                                    int* __restrict__ part, int N) {
    int t = threadIdx.x, lane = t & 63, wid = t >> 6;
    int i = blockIdx.x * 256 + t;
    int v = (i < N) ? deg[i] + 1 : 0;
#pragma unroll
    for (int off = 32; off > 0; off >>= 1) v += __shfl_xor(v, off);
    __shared__ int ws4[4];
    if (lane == 0) ws4[wid] = v;
    __syncthreads();
    if (t == 0) part[blockIdx.x] = ws4[0] + ws4[1] + ws4[2] + ws4[3];
}

// scanC with inline lookback: base = sum(part[0..b)) computed directly (nb ~ 196
// ints, L2-hot). Last block writes rowptr[N].
__global__ __launch_bounds__(256) void scanC_kernel(const int* __restrict__ deg,
                                                    const int* __restrict__ part,
                                                    int* __restrict__ rowptr,
                                                    int* __restrict__ cursor, int N) {
    int t = threadIdx.x, lane = t & 63, wid = t >> 6;
    int b = blockIdx.x;
    __shared__ int ws[4];
    // base = sum part[0..b)
    int acc = 0;
    for (int c0 = 0; c0 < b; c0 += 256) {
        int idx = c0 + t;
        int v = (idx < b) ? part[idx] : 0;
#pragma unroll
        for (int off = 32; off > 0; off >>= 1) v += __shfl_xor(v, off);
        if (lane == 0) ws[wid] = v;
        __syncthreads();
        acc += ws[0] + ws[1] + ws[2] + ws[3];
        __syncthreads();
    }
    // in-chunk exclusive scan of deg+1
    int i = b * 256 + t;
    int v = (i < N) ? deg[i] + 1 : 0;
    int x = v;
#pragma unroll
    for (int off = 1; off < 64; off <<= 1) {
        int u = __shfl_up(x, off);
        if (lane >= off) x += u;
    }
    if (lane == 63) ws[wid] = x;
    __syncthreads();
    int base = acc;
    for (int w = 0; w < wid; ++w) base += ws[w];
    int excl = base + x - v;
    if (i < N) { rowptr[i] = excl; cursor[i] = excl; }
    if (b == (int)gridDim.x - 1 && t == 0)
        rowptr[N] = acc + ws[0] + ws[1] + ws[2] + ws[3];
}

// ---- K5: fused per-node GATv2 + residual + LayerNorm. One wave per node.
// R10: xl gather is now int8+scale (512 B row + 32 B scale vs 1024 B): halves the
// logical gather volume that was at ~95% of the streaming ceiling. Dequant via
// v_cvt_f32_ubyteN + fma (+8 VALU per 8 vals). Depth-2 pipeline, DPP reduce,
// register pin, __launch_bounds__(256,2) kept.
__global__ __launch_bounds__(256, 2) void agg_kernel(
    const uint2* __restrict__ xlq, const float* __restrict__ sclp,
    bf16* __restrict__ xr,
    const void* __restrict__ xv, const int* __restrict__ rowptr,
    const int* __restrict__ srcs, const float* __restrict__ smalls,
    int N, const int* __restrict__ flags) {
    int n = blockIdx.x * 4 + (threadIdx.x >> 6);
    if (n >= N) return;
    int lane = threadIdx.x & 63;
    int h = lane >> 4, cg = lane & 15;
    const float* att = smalls + 1024;
    const float* gat_bias = smalls + 1536;
    const float* ln_g = smalls + 1664;
    const float* ln_b = smalls + 1792;

    float att_f[8];
    {
        const float4* ap = (const float4*)(att + (size_t)h * 128 + cg * 8);
        float4 a0 = ap[0], a1 = ap[1];
        att_f[0] = a0.x; att_f[1] = a0.y; att_f[2] = a0.z; att_f[3] = a0.w;
        att_f[4] = a1.x; att_f[5] = a1.y; att_f[6] = a1.z; att_f[7] = a1.w;
    }
    float xr_f[8];
    uint4 xw = ((const uint4*)(xr + (size_t)n * 512))[lane];
    unpack8(xw, xr_f);

    float o[8];
#pragma unroll
    for (int j = 0; j < 8; ++j) o[j] = 0.f;
    float lsum = 0.f;

    int beg = rowptr[n], end = rowptr[n + 1];
    int last = end - 1;
    int sci = lane >> 3;   // scale chunk for this lane's 8 slots
    int sA = srcs[beg];
    int sB = srcs[min(beg + 1, last)];
    uint2 lw = xlq[(size_t)sA * 64 + lane];
    float lsc = sclp[(size_t)sA * 8 + sci];
    for (int i = beg; i < end; ++i) {
        uint2 cur = lw;
        float cs = lsc;
        int snext = sB;
        sB = srcs[min(i + 2, last)];
        lw = xlq[(size_t)snext * 64 + lane];
        lsc = sclp[(size_t)snext * 8 + sci];
        float mb = cs * -128.f;
        float v[8];
        v[0] = fmaf(ub2f(cur.x, 0), cs, mb);
        v[1] = fmaf(ub2f(cur.x, 1), cs, mb);
        v[2] = fmaf(ub2f(cur.x, 2), cs, mb);
        v[3] = fmaf(ub2f(cur.x, 3), cs, mb);
        v[4] = fmaf(ub2f(cur.y, 0), cs, mb);
        v[5] = fmaf(ub2f(cur.y, 1), cs, mb);
        v[6] = fmaf(ub2f(cur.y, 2), cs, mb);
        v[7] = fmaf(ub2f(cur.y, 3), cs, mb);
        // lrelu(z)*a summed == 0.6*(z.a) + 0.4*(|z|.a)
        float dotA = 0.f, dotB = 0.f;
#pragma unroll
        for (int j = 0; j < 8; ++j) {
            float z = v[j] + xr_f[j];
            dotA = fmaf(z, att_f[j], dotA);
            dotB = fmaf(fabsf(z), att_f[j], dotB);
        }
        float p = fmaf(0.4f, dotB, 0.6f * dotA);
        // all-lanes sum within the 16-lane head group (DPP rotation reduce)
        p = ror_add16<0x128>(p);  // row_ror:8
        p = ror_add16<0x124>(p);  // row_ror:4
        p = ror_add16<0x122>(p);  // row_ror:2
        p = ror_add16<0x121>(p);  // row_ror:1
        float w = __expf(fminf(p, 60.f));
        lsum += w;
#pragma unroll
        for (int j = 0; j < 8; ++j) o[j] = fmaf(w, v[j], o[j]);
        // Pin persistent state in arch VGPRs (emits nothing; defeats remat/AGPR-shuffle).
        asm volatile("" : "+v"(o[0]), "+v"(o[1]), "+v"(o[2]), "+v"(o[3]),
                          "+v"(o[4]), "+v"(o[5]), "+v"(o[6]), "+v"(o[7]),
                          "+v"(lsum),
                          "+v"(att_f[0]), "+v"(att_f[1]), "+v"(att_f[2]), "+v"(att_f[3]),
                          "+v"(att_f[4]), "+v"(att_f[5]), "+v"(att_f[6]), "+v"(att_f[7]),
                          "+v"(xr_f[0]), "+v"(xr_f[1]), "+v"(xr_f[2]), "+v"(xr_f[3]),
                          "+v"(xr_f[4]), "+v"(xr_f[5]), "+v"(xr_f[6]), "+v"(xr_f[7]));
    }
    float inv = 0.25f / lsum;
#pragma unroll
    for (int j = 0; j < 8; ++j) o[j] *= inv;
#pragma unroll
    for (int j = 0; j < 8; ++j) {
        o[j] += __shfl_xor(o[j], 16);
        o[j] += __shfl_xor(o[j], 32);
    }
    // residual x (std order): slot t of lane -> std channels bc+16c (+1 for t>=4)
    int bc = 64 * (cg >> 3) + 2 * (cg & 7);
    float xf[8];
    if (flags[0]) {
#pragma unroll
        for (int c = 0; c < 4; ++c) {
            unsigned d = *(const unsigned*)((const unsigned short*)xv + (size_t)n * 128 + bc + 16 * c);
            xf[c] = bits2f(d); xf[c + 4] = hi2f(d);
        }
    } else {
#pragma unroll
        for (int c = 0; c < 4; ++c) {
            float2 f = *(const float2*)((const float*)xv + (size_t)n * 128 + bc + 16 * c);
            xf[c] = f.x; xf[c + 4] = f.y;
        }
    }
    float gb[8];
    {
        const float4* gp = (const float4*)(gat_bias + cg * 8);
        float4 a0 = gp[0], a1 = gp[1];
        gb[0] = a0.x; gb[1] = a0.y; gb[2] = a0.z; gb[3] = a0.w;
        gb[4] = a1.x; gb[5] = a1.y; gb[6] = a1.z; gb[7] = a1.w;
    }
    float vl[8];
    float s1v = 0.f;
#pragma unroll
    for (int j = 0; j < 8; ++j) { vl[j] = xf[j] + o[j] + gb[j]; s1v += vl[j]; }
    s1v += __shfl_xor(s1v, 1); s1v += __shfl_xor(s1v, 2);
    s1v += __shfl_xor(s1v, 4); s1v += __shfl_xor(s1v, 8);
    float mu = s1v * (1.f / 128.f);
    float s2v = 0.f;
#pragma unroll
    for (int j = 0; j < 8; ++j) { float d = vl[j] - mu; s2v += d * d; }
    s2v += __shfl_xor(s2v, 1); s2v += __shfl_xor(s2v, 2);
    s2v += __shfl_xor(s2v, 4); s2v += __shfl_xor(s2v, 8);
    float rinv = rsqrtf(s2v * (1.f / 128.f) + LN_EPS);
    if (h == 0) {  // lanes 0..15: hn slot-bf16 -> bytes 0..255 of the xr row
        float g[8], bt[8];
        const float4* gp = (const float4*)(ln_g + cg * 8);
        float4 g0 = gp[0], g1 = gp[1];
        g[0] = g0.x; g[1] = g0.y; g[2] = g0.z; g[3] = g0.w;
        g[4] = g1.x; g[5] = g1.y; g[6] = g1.z; g[7] = g1.w;
        const float4* bp = (const float4*)(ln_b + cg * 8);
        float4 b0 = bp[0], b1v = bp[1];
        bt[0] = b0.x; bt[1] = b0.y; bt[2] = b0.z; bt[3] = b0.w;
        bt[4] = b1v.x; bt[5] = b1v.y; bt[6] = b1v.z; bt[7] = b1v.w;
        float hnv[8];
#pragma unroll
        for (int j = 0; j < 8; ++j) hnv[j] = (vl[j] - mu) * rinv * g[j] + bt[j];
        char* rowp = (char*)xr + (size_t)n * 1024;
        uint4 pk;
        pk.x = (unsigned)f2b_bits(hnv[0]) | ((unsigned)f2b_bits(hnv[1]) << 16);
        pk.y = (unsigned)f2b_bits(hnv[2]) | ((unsigned)f2b_bits(hnv[3]) << 16);
        pk.z = (unsigned)f2b_bits(hnv[4]) | ((unsigned)f2b_bits(hnv[5]) << 16);
        pk.w = (unsigned)f2b_bits(hnv[6]) | ((unsigned)f2b_bits(hnv[7]) << 16);
        *(uint4*)(rowp + cg * 16) = pk;
    }
}

// ---- K6: fused FFN: mid = lrelu(hn@W1+b1) in LDS; out = mid@W2 + hn + b2
// A staged via LDS (coalesced), W1t/W2x fragment-ordered (1 KB contiguous per
// B-load). Epilogue stages C in the dead LDS buffer, then writes flat-contiguous.
__global__ __launch_bounds__(256) void ffn_fused_kernel(
    const char* __restrict__ hnrows, const unsigned short* __restrict__ W1t,
    const unsigned short* __restrict__ W2x, const float* __restrict__ smalls,
    void* __restrict__ outv, int N, const int* __restrict__ flags) {
    __shared__ __align__(16) char lds[64 * 528];   // A-stage [64][272] -> mid [64][528] -> C [64][132 f32]
    const float* b1 = smalls + 1920;
    const float* b2v = smalls + 2176;
    int tt = (int)threadIdx.x;
    int wid = threadIdx.x >> 6, lane = threadIdx.x & 63;
    int quad = lane >> 4, l16 = lane & 15;
    int m0 = blockIdx.x * 64;

    // stage A (hn slot-bf16 rows, 256 B each) into LDS, coalesced
#pragma unroll
    for (int s = 0; s < 4; ++s) {
        int row = s * 16 + (tt >> 4);
        int gr = m0 + row; gr = (gr < N) ? gr : N - 1;
        uint4 v = *(const uint4*)(hnrows + (size_t)gr * 1024 + (tt & 15) * 16);
        *(uint4*)(lds + row * 272 + (tt & 15) * 16) = v;
    }
    __syncthreads();
    short8 A[4][4];  // hn slot-bf16, kept for the residual K-extension
#pragma unroll
    for (int rf = 0; rf < 4; ++rf)
#pragma unroll
        for (int k4 = 0; k4 < 4; ++k4)
            A[rf][k4] = ld8b(lds + (rf * 16 + l16) * 272 + (k4 * 32 + quad * 8) * 2);
    __syncthreads();   // A in regs; lds free for mid

    // ---- phase 1: mid cols n0..n0+63, all 64 rows ----
    {
        int n0 = wid * 64;
        f32x4 acc[4][4];
#pragma unroll
        for (int rf = 0; rf < 4; ++rf)
#pragma unroll
            for (int c = 0; c < 4; ++c) acc[rf][c] = (f32x4){0.f, 0.f, 0.f, 0.f};
#pragma unroll
        for (int k4 = 0; k4 < 4; ++k4) {
            short8 b[4];
#pragma unroll
            for (int c = 0; c < 4; ++c)
                b[c] = ld8b((const char*)(W1t + (((size_t)(wid * 4 + c) * 4 + k4) * 64 + lane) * 8));
#pragma unroll
            for (int rf = 0; rf < 4; ++rf)
#pragma unroll
                for (int c = 0; c < 4; ++c)
                    acc[rf][c] = __builtin_amdgcn_mfma_f32_16x16x32_bf16(A[rf][k4], b[c], acc[rf][c], 0, 0, 0);
        }
        float bv[4];
#pragma unroll
        for (int c = 0; c < 4; ++c) bv[c] = b1[n0 + c * 16 + l16];
#pragma unroll
        for (int rf = 0; rf < 4; ++rf) {
#pragma unroll
            for (int j = 0; j < 4; ++j) {
                int lrow = rf * 16 + quad * 4 + j;
                uint2 pk;
                pk.x = (unsigned)f2b_bits(lrelu(acc[rf][0][j] + bv[0])) |
                       ((unsigned)f2b_bits(lrelu(acc[rf][1][j] + bv[1])) << 16);
                pk.y = (unsigned)f2b_bits(lrelu(acc[rf][2][j] + bv[2])) |
                       ((unsigned)f2b_bits(lrelu(acc[rf][3][j] + bv[3])) << 16);
                *(uint2*)(lds + lrow * 528 + (n0 + 4 * l16) * 2) = pk;
            }
        }
    }
    __syncthreads();
    // ---- phase 2: out rows rh*32..+31, cols nh*64..+63; K=256 (LDS) + 128 (regs) ----
    int rh = wid >> 1, nh = wid & 1;
    int n0b = nh * 64;
    f32x4 a2[2][4];
#pragma unroll
    for (int rfl = 0; rfl < 2; ++rfl)
#pragma unroll
        for (int c = 0; c < 4; ++c) a2[rfl][c] = (f32x4){0.f, 0.f, 0.f, 0.f};
#pragma unroll
    for (int kk = 0; kk < 256; kk += 32) {
        int k4 = kk >> 5;
        short8 am[2], b[4];
#pragma unroll
        for (int rfl = 0; rfl < 2; ++rfl)
            am[rfl] = ld8b(lds + (rh * 32 + rfl * 16 + l16) * 528 + (kk + quad * 8) * 2);
#pragma unroll
        for (int c = 0; c < 4; ++c)
            b[c] = ld8b((const char*)(W2x + (((size_t)(nh * 4 + c) * 12 + k4) * 64 + lane) * 8));
#pragma unroll
        for (int rfl = 0; rfl < 2; ++rfl)
#pragma unroll
            for (int c = 0; c < 4; ++c)
                a2[rfl][c] = __builtin_amdgcn_mfma_f32_16x16x32_bf16(am[rfl], b[c], a2[rfl][c], 0, 0, 0);
    }
#pragma unroll
    for (int k4 = 0; k4 < 4; ++k4) {  // residual: hn slot regs x perm-identity (K blocks 8..11)
        short8 b[4];
#pragma unroll
        for (int c = 0; c < 4; ++c)
            b[c] = ld8b((const char*)(W2x + (((size_t)(nh * 4 + c) * 12 + 8 + k4) * 64 + lane) * 8));
#pragma unroll
        for (int rfl = 0; rfl < 2; ++rfl)
#pragma unroll
            for (int c = 0; c < 4; ++c)
                a2[rfl][c] = __builtin_amdgcn_mfma_f32_16x16x32_bf16(A[rh * 2 + rfl][k4], b[c], a2[rfl][c], 0, 0, 0);
    }
    // ---- epilogue: stage C into LDS (mid dead after kk loop), write coalesced ----
    __syncthreads();   // all waves done reading mid
#pragma unroll
    for (int c = 0; c < 4; ++c) {
        int col = n0b + c * 16 + l16;
        float bv = b2v[col];
#pragma unroll
        for (int rfl = 0; rfl < 2; ++rfl) {
#pragma unroll
            for (int j = 0; j < 4; ++j) {
                int lrow = rh * 32 + rfl * 16 + quad * 4 + j;
                *(float*)(lds + lrow * 528 + col * 4) = a2[rfl][c][j] + bv;
            }
        }
    }
    __syncthreads();
    int isb = flags[0];
    int t = (int)threadIdx.x;
    if (isb) {
        // flat bf16 tile: 64 rows x 128 = 8192 vals; 4 steps x 256 threads x 8 vals.
#pragma unroll
        for (int k = 0; k < 4; ++k) {
            int f = t * 8 + k * 2048;          // flat val index
            int lrow = f >> 7, col = f & 127;
            int row = m0 + lrow;
            if (row < N) {
                const float* src = (const float*)(lds + lrow * 528) + col;
                uint4 pk;
                pk.x = (unsigned)f2b_bits(src[0]) | ((unsigned)f2b_bits(src[1]) << 16);
                pk.y = (unsigned)f2b_bits(src[2]) | ((unsigned)f2b_bits(src[3]) << 16);
                pk.z = (unsigned)f2b_bits(src[4]) | ((unsigned)f2b_bits(src[5]) << 16);
                pk.w = (unsigned)f2b_bits(src[6]) | ((unsigned)f2b_bits(src[7]) << 16);
                *(uint4*)((unsigned short*)outv + (size_t)row * 128 + col) = pk;
            }
        }
    } else {
        // flat f32 tile: 8 steps x 256 threads x 4 vals.
#pragma unroll
        for (int k = 0; k < 8; ++k) {
            int f = t * 4 + k * 1024;
            int lrow = f >> 7, col = f & 127;
            int row = m0 + lrow;
            if (row < N) {
                const float* src = (const float*)(lds + lrow * 528) + col;
                float4 v = *(const float4*)src;
                *(float4*)((float*)outv + (size_t)row * 128 + col) = v;
            }
        }
    }
}

extern "C" void kernel_launch(void* const* d_in, const int* in_sizes, int n_in,
                              void* d_out, int out_size, void* d_ws, size_t ws_size,
                              hipStream_t stream) {
    const void* x = d_in[0];
    const int* ei = (const int*)d_in[1];

    int N = in_sizes[0] / 128;
    int E = in_sizes[1] / 2;
    int ET = E + N;
    int nb = (N + 255) / 256;

    // ---- workspace layout (~80 MB)
    char* base = (char*)d_ws;
    int* flags = (int*)base;
    size_t off = 256;
    float* smalls = (float*)(base + off);               off += 2304 * 4;
    off = (off + 255) & ~(size_t)255;
    unsigned short* Wlt = (unsigned short*)(base + off); off += 512 * 128 * 2;
    unsigned short* Wrt = (unsigned short*)(base + off); off += 512 * 128 * 2;
    unsigned short* W1t = (unsigned short*)(base + off); off += 256 * 128 * 2;
    unsigned short* W2x = (unsigned short*)(base + off); off += 128 * 384 * 2;
    off = (off + 1023) & ~(size_t)1023;
    unsigned char* xl8 = (unsigned char*)(base + off);  off += (size_t)N * 512;   // int8 xl rows
    off = (off + 255) & ~(size_t)255;
    float* sclp = (float*)(base + off);                 off += (size_t)N * 8 * 4; // per-(row,chunk) scales
    off = (off + 1023) & ~(size_t)1023;
    bf16* xr = (bf16*)(base + off);   off += (size_t)N * 512 * 2;  // rows reused: hn slot bf16 (256 B)
    int* srcs = (int*)(base + off);   off += (size_t)ET * 4;
    int* rowptr = (int*)(base + off); off += (size_t)(N + 1) * 4;
    int* deg = (int*)(base + off);    off += (size_t)N * 4;
    int* cursor = (int*)(base + off); off += (size_t)N * 4;
    int* part = (int*)(base + off);   off += (size_t)nb * 4;
    const char* hnrows = (const char*)xr;

    // deg zero-init (hist folded into prep seg 4)
    hipMemsetAsync(deg, 0, (size_t)N * 4, stream);

    detect_kernel<<<1, 64, 0, stream>>>((const unsigned*)x, ei, flags, E);

    PrepArgs pa;
    pa.Wl = d_in[2]; pa.Wr = d_in[4]; pa.W1 = d_in[10]; pa.W2 = d_in[12];
    pa.ssrc[0] = d_in[3];  pa.ssrc[1] = d_in[5];  pa.ssrc[2] = d_in[6];
    pa.ssrc[3] = d_in[7];  pa.ssrc[4] = d_in[8];  pa.ssrc[5] = d_in[9];
    pa.ssrc[6] = d_in[11]; pa.ssrc[7] = d_in[13];
    pa.ei = ei;
    pa.Wlt = Wlt; pa.Wrt = Wrt; pa.W1t = W1t; pa.W2x = W2x;
    pa.smalls = smalls; pa.deg = deg; pa.N = N; pa.E = E;
    int px = (E > 65536 ? E : 65536);
    prep_kernel<<<dim3((px + 255) / 256, 6), 256, 0, stream>>>(pa, flags);

    // CSR scans first (depend only on prep's hist) ...
    scanA_kernel<<<nb, 256, 0, stream>>>(deg, part, N);
    scanC_kernel<<<nb, 256, 0, stream>>>(deg, part, rowptr, cursor, N);

    // ... then proj and scatter share ONE dispatch (independent chains join here)
    int g64 = (N + 63) / 64;
    int scb = (ET + 255) / 256;
    proj_scatter_kernel<<<g64 + scb, 256, 0, stream>>>(
        x, Wlt, Wrt, smalls, xl8, sclp, (unsigned short*)xr,
        ei, cursor, srcs, N, E, ET, g64, flags);

    agg_kernel<<<(N + 3) / 4, 256, 0, stream>>>((const uint2*)xl8, sclp, xr, x,
                                                rowptr, srcs, smalls, N, flags);

    ffn_fused_kernel<<<g64, 256, 0, stream>>>(hnrows, W1t, W2x, smalls, d_out, N, flags);
}

// Round 12
// 297.816 us; speedup vs baseline: 1.0725x; 1.0725x over previous
//
#include <hip/hip_runtime.h>
#include <hip/hip_bf16.h>
#include <stdint.h>

typedef __hip_bfloat16 bf16;
typedef __attribute__((ext_vector_type(8))) short short8;
typedef __attribute__((ext_vector_type(4))) float f32x4;

#define NEG 0.2f
#define LN_EPS 1e-5f

// Channel permutation (per 64-block): slot = 64a + 4*l + c  <->  std = 64a + 16c + l
__device__ __host__ __forceinline__ int stdch(int q) {
    return (q & ~63) | (16 * (q & 3)) | ((q & 63) >> 2);
}

__device__ __forceinline__ float bits2f(unsigned b) {  // low 16 bits = bf16
    return __uint_as_float(b << 16);
}
__device__ __forceinline__ float hi2f(unsigned b) {    // high 16 bits = bf16
    return __uint_as_float(b & 0xffff0000u);
}
__device__ __forceinline__ unsigned short f2b_bits(float f) {  // RNE f32->bf16 bits
    unsigned u = __float_as_uint(f);
    unsigned r = u + 0x7fffu + ((u >> 16) & 1u);
    return (unsigned short)(r >> 16);
}
__device__ __forceinline__ float lrelu(float v) {
    return fmaxf(v, 0.f) + NEG * fminf(v, 0.f);
}
__device__ __forceinline__ void unpack8(uint4 u, float* v) {
    v[0] = bits2f(u.x); v[1] = hi2f(u.x);
    v[2] = bits2f(u.y); v[3] = hi2f(u.y);
    v[4] = bits2f(u.z); v[5] = hi2f(u.z);
    v[6] = bits2f(u.w); v[7] = hi2f(u.w);
}

union S8 { uint4 u; short8 s; unsigned short us[8]; };
__device__ __forceinline__ short8 ld8b(const char* p) {
    S8 c; c.u = *(const uint4*)p; return c.s;
}
__device__ __forceinline__ short8 ld8f(const float* p) {
    float4 a = ((const float4*)p)[0], b = ((const float4*)p)[1];
    S8 c;
    c.us[0] = f2b_bits(a.x); c.us[1] = f2b_bits(a.y);
    c.us[2] = f2b_bits(a.z); c.us[3] = f2b_bits(a.w);
    c.us[4] = f2b_bits(b.x); c.us[5] = f2b_bits(b.y);
    c.us[6] = f2b_bits(b.z); c.us[7] = f2b_bits(b.w);
    return c.s;
}

// All-lanes sum within each 16-lane row via DPP row_ror rotation-reduce
template <int CTRL>
__device__ __forceinline__ float ror_add16(float x) {
    int xi = __float_as_int(x);
    int r = __builtin_amdgcn_update_dpp(xi, xi, CTRL, 0xf, 0xf, false);
    return x + __int_as_float(r);
}

// ---- K0: detect float dtype (flags[0]=1 -> bf16) and index width (flags[1]=1 -> int64)
__global__ void detect_kernel(const unsigned* __restrict__ xw, const int* __restrict__ ei,
                              int* __restrict__ flags, int E) {
    int lane = threadIdx.x;  // 64 threads
    int sane = 0;
    for (int k = 0; k < 4; ++k) {
        unsigned short lo = (unsigned short)(xw[k * 64 + lane] & 0xFFFFu);
        int ex = (lo >> 7) & 0xFF;
        if (lo == 0 || (ex > 100 && ex < 155)) sane++;
    }
#pragma unroll
    for (int off = 32; off > 0; off >>= 1) sane += __shfl_xor(sane, off);
    int nchk = E < 64 ? E : 64;
    int bad = (lane < nchk) ? (ei[2 * lane + 1] != 0) : 0;
    unsigned long long bb = __ballot(bad);
    if (lane == 0) {
        flags[0] = (sane > 200) ? 1 : 0;
        flags[1] = (bb == 0ULL) ? 1 : 0;
    }
}

// ---- K1: prep: fragment-ordered weight tables (1 KB contiguous per B-load),
//          small cvt, edge histogram.
// Layout: W[(nb*K4 + k4)*64 + lane]*8 + j  where col = nb*16+(lane&15),
//         k = k4*32+(lane>>4)*8+j.  K4 = K/32.
struct PrepArgs {
    const void* Wl; const void* Wr; const void* W1; const void* W2;
    const void* ssrc[8];   // b_l, b_r, att, gat_bias, ln_g, ln_b, b1, b2
    const int* ei;
    unsigned short* Wlt; unsigned short* Wrt; unsigned short* W1t; unsigned short* W2x;
    float* smalls;         // 2304 floats
    int* deg;
    int N; int E;
};
__device__ __forceinline__ float cvt_one(const void* p, int idx, int isb) {
    return isb ? bits2f(((const unsigned short*)p)[idx]) : ((const float*)p)[idx];
}
__global__ __launch_bounds__(256) void prep_kernel(PrepArgs a, const int* __restrict__ flags) {
    int isb = flags[0];
    int i = blockIdx.x * 256 + threadIdx.x;
    int seg = blockIdx.y;
    if (seg == 0) {         // Wlt frag-order (512 cols, K=128, K4=4, nb 0..31)
        if (i < 512 * 128) {
            int j = i & 7, lane = (i >> 3) & 63, k4 = (i >> 9) & 3, nb = i >> 11;
            int col = nb * 16 + (lane & 15);
            int k = k4 * 32 + (lane >> 4) * 8 + j;
            a.Wlt[i] = isb ? ((const unsigned short*)a.Wl)[k * 512 + col]
                           : f2b_bits(((const float*)a.Wl)[k * 512 + col]);
        }
    } else if (seg == 1) {  // Wrt frag-order
        if (i < 512 * 128) {
            int j = i & 7, lane = (i >> 3) & 63, k4 = (i >> 9) & 3, nb = i >> 11;
            int col = nb * 16 + (lane & 15);
            int k = k4 * 32 + (lane >> 4) * 8 + j;
            a.Wrt[i] = isb ? ((const unsigned short*)a.Wr)[k * 512 + col]
                           : f2b_bits(((const float*)a.Wr)[k * 512 + col]);
        }
    } else if (seg == 2) {  // W1t frag-order (256 cols, K=128 in hn slot order, nb 0..15)
        if (i < 256 * 128) {
            int j = i & 7, lane = (i >> 3) & 63;
            int r2 = i >> 9;          // 0..63
            int k4 = r2 & 3, nb = r2 >> 2;
            int col = nb * 16 + (lane & 15);
            int q = k4 * 32 + (lane >> 4) * 8 + j;   // slot-k
            int k = stdch(q);
            a.W1t[i] = isb ? ((const unsigned short*)a.W1)[k * 256 + col]
                           : f2b_bits(((const float*)a.W1)[k * 256 + col]);
        }
    } else if (seg == 3) {  // W2x frag-order (128 cols, K=384: 256 W2 + 128 perm-identity)
        if (i < 128 * 384) {
            int j = i & 7, lane = (i >> 3) & 63;
            int r2 = i >> 9;          // 0..95
            int k4 = r2 % 12, nb = r2 / 12;
            int col = nb * 16 + (lane & 15);
            int p = k4 * 32 + (lane >> 4) * 8 + j;   // 0..383
            if (p < 256) {
                int k = stdch(p);
                a.W2x[i] = isb ? ((const unsigned short*)a.W2)[k * 128 + col]
                               : f2b_bits(((const float*)a.W2)[k * 128 + col]);
            } else {
                int q = p - 256;
                a.W2x[i] = (stdch(q) == col) ? (unsigned short)0x3F80 : (unsigned short)0;
            }
        }
    } else if (seg == 4) {  // edge histogram (deg pre-zeroed by hipMemsetAsync)
        if (i < a.E) {
            int d = flags[1] ? a.ei[2 * (size_t)a.E + 2 * (size_t)i] : a.ei[(size_t)a.E + i];
            if ((unsigned)d >= (unsigned)a.N) d = 0;
            atomicAdd(&a.deg[d], 1);
        }
    } else {                // smalls: b_l[0,512) b_r[512,1024) att_p[1024,1536)
                            //         gb_p[1536,1664) lng_p[1664,1792) lnb_p[1792,1920)
                            //         b1[1920,2176) b2[2176,2304)
        if (i < 512) a.smalls[i] = cvt_one(a.ssrc[0], i, isb);
        else if (i < 1024) a.smalls[i] = cvt_one(a.ssrc[1], i - 512, isb);
        else if (i < 1536) {
            int j = i - 1024, h = j >> 7, q = j & 127;
            a.smalls[i] = cvt_one(a.ssrc[2], h * 128 + stdch(q), isb);
        } else if (i < 1664) a.smalls[i] = cvt_one(a.ssrc[3], stdch(i - 1536), isb);
        else if (i < 1792)   a.smalls[i] = cvt_one(a.ssrc[4], stdch(i - 1664), isb);
        else if (i < 1920)   a.smalls[i] = cvt_one(a.ssrc[5], stdch(i - 1792), isb);
        else if (i < 2176)   a.smalls[i] = cvt_one(a.ssrc[6], i - 1920, isb);
        else if (i < 2304)   a.smalls[i] = cvt_one(a.ssrc[7], i - 2176, isb);
    }
}

// ================= MFMA GEMM =================
// A (16x32): lane holds A[m=lane&15][k=quad*8+j]; B (32x16): B[k=quad*8+j][n=lane&15]
// C/D: reg j -> row=quad*4+j, col=lane&15.  (m89/m91-verified)

// ---- K2: merged proj + scatter. (R10-verified form, 302.1 µs total.)
// Fragment-ordered weights (1 KB contiguous per B-load) + A staged via LDS
// (coalesced global, 2-way-conflict ds_read fragments): fixed the R9-diagnosed
// L1-transaction wall. scatter rides as tail blocks in the same dispatch.
// R11 ERRATA: in-loop int8 quantization of xl (DPP-max + rintf against live
// accs) blew VGPR 120->152, occupancy ->9.5%, +400K bank conflicts, proj +10 µs,
// with no visible agg win -- reverted.
__global__ __launch_bounds__(256) void proj_scatter_kernel(
    const void* __restrict__ xv, const unsigned short* __restrict__ Wlt,
    const unsigned short* __restrict__ Wrt, const float* __restrict__ smalls,
    unsigned short* __restrict__ xl, unsigned short* __restrict__ xr,
    const int* __restrict__ ei, int* __restrict__ cursor, int* __restrict__ srcs,
    int N, int E, int ET, int gproj, const int* __restrict__ flags) {
    if ((int)blockIdx.x >= gproj) {
        // ---- scatter tail blocks ----
        int e = ((int)blockIdx.x - gproj) * 256 + (int)threadIdx.x;
        if (e >= ET) return;
        int s, d;
        if (e < E) {
            if (flags[1]) { s = ei[2 * (size_t)e]; d = ei[2 * (size_t)E + 2 * (size_t)e]; }
            else          { s = ei[e];             d = ei[(size_t)E + e]; }
        } else { s = e - E; d = s; }
        if ((unsigned)s >= (unsigned)N) s = 0;
        if ((unsigned)d >= (unsigned)N) d = 0;
        int pos = atomicAdd(&cursor[d], 1);
        srcs[pos] = s;
        return;
    }
    // ---- proj body ----
    __shared__ __align__(16) unsigned short alds[64 * 136];  // 272-B row stride
    int isb = flags[0];
    int tt = (int)threadIdx.x;
    int wid = threadIdx.x >> 6, lane = threadIdx.x & 63;
    int quad = lane >> 4, l16 = lane & 15;
    int m0 = blockIdx.x * 64;

    // stage A (64 rows x 256 B bf16) into LDS, coalesced 16 B/thread
#pragma unroll
    for (int s = 0; s < 4; ++s) {
        int row = s * 16 + (tt >> 4);
        int gr = m0 + row; gr = (gr < N) ? gr : N - 1;
        S8 c8;
        if (isb) c8.u = *(const uint4*)((const char*)xv + (size_t)gr * 256 + (tt & 15) * 16);
        else     c8.s = ld8f((const float*)xv + (size_t)gr * 128 + (tt & 15) * 8);
        *(uint4*)(alds + row * 136 + (tt & 15) * 8) = c8.u;
    }
    __syncthreads();
    short8 A[4][4];
#pragma unroll
    for (int rf = 0; rf < 4; ++rf)
#pragma unroll
        for (int k4 = 0; k4 < 4; ++k4)
            A[rf][k4] = ld8b((const char*)(alds + (rf * 16 + l16) * 136 + k4 * 32 + quad * 8));

    for (int iter = 0; iter < 4; ++iter) {
        const unsigned short* Wt = (iter < 2) ? Wlt : Wrt;
        const float* bias = smalls + ((iter < 2) ? 0 : 512);
        unsigned short* out = (iter < 2) ? xl : xr;
        int n0 = (iter & 1) * 256 + wid * 64;
        int nb0 = n0 >> 4;

        f32x4 acc[4][4];
#pragma unroll
        for (int rf = 0; rf < 4; ++rf)
#pragma unroll
            for (int c = 0; c < 4; ++c) acc[rf][c] = (f32x4){0.f, 0.f, 0.f, 0.f};

#pragma unroll
        for (int k4 = 0; k4 < 4; ++k4) {
            short8 b[4];
#pragma unroll
            for (int c = 0; c < 4; ++c)
                b[c] = ld8b((const char*)(Wt + (((size_t)(nb0 + c) * 4 + k4) * 64 + lane) * 8));
#pragma unroll
            for (int rf = 0; rf < 4; ++rf)
#pragma unroll
                for (int c = 0; c < 4; ++c)
                    acc[rf][c] = __builtin_amdgcn_mfma_f32_16x16x32_bf16(A[rf][k4], b[c], acc[rf][c], 0, 0, 0);
        }
        float bv[4];
#pragma unroll
        for (int c = 0; c < 4; ++c) bv[c] = bias[n0 + c * 16 + l16];
#pragma unroll
        for (int rf = 0; rf < 4; ++rf) {
#pragma unroll
            for (int j = 0; j < 4; ++j) {
                int row = m0 + rf * 16 + quad * 4 + j;
                if (row < N) {
                    uint2 pk;
                    pk.x = (unsigned)f2b_bits(acc[rf][0][j] + bv[0]) |
                           ((unsigned)f2b_bits(acc[rf][1][j] + bv[1]) << 16);
                    pk.y = (unsigned)f2b_bits(acc[rf][2][j] + bv[2]) |
                           ((unsigned)f2b_bits(acc[rf][3][j] + bv[3]) << 16);
                    *(uint2*)(out + (size_t)row * 512 + n0 + 4 * l16) = pk;
                }
            }
        }
    }
}

// ---- CSR build (deg holds edge-count only; +1 self-loop folded into scans) ----
__global__ __launch_bounds__(256) void scanA_kernel(const int* __restrict__ deg,
                                                    int* __restrict__ part, int N) {
    int t = threadIdx.x, lane = t & 63, wid = t >> 6;
    int i = blockIdx.x * 256 + t;
    int v = (i < N) ? deg[i] + 1 : 0;
#pragma unroll
    for (int off = 32; off > 0; off >>= 1) v += __shfl_xor(v, off);
    __shared__ int ws4[4];
    if (lane == 0) ws4[wid] = v;
    __syncthreads();
    if (t == 0) part[blockIdx.x] = ws4[0] + ws4[1] + ws4[2] + ws4[3];
}

// scanC with inline lookback: base = sum(part[0..b)) computed directly (nb ~ 196
// ints, L2-hot). Last block writes rowptr[N].
__global__ __launch_bounds__(256) void scanC_kernel(const int* __restrict__ deg,
                                                    const int* __restrict__ part,
                                                    int* __restrict__ rowptr,
                                                    int* __restrict__ cursor, int N) {
    int t = threadIdx.x, lane = t & 63, wid = t >> 6;
    int b = blockIdx.x;
    __shared__ int ws[4];
    // base = sum part[0..b)
    int acc = 0;
    for (int c0 = 0; c0 < b; c0 += 256) {
        int idx = c0 + t;
        int v = (idx < b) ? part[idx] : 0;
#pragma unroll
        for (int off = 32; off > 0; off >>= 1) v += __shfl_xor(v, off);
        if (lane == 0) ws[wid] = v;
        __syncthreads();
        acc += ws[0] + ws[1] + ws[2] + ws[3];
        __syncthreads();
    }
    // in-chunk exclusive scan of deg+1
    int i = b * 256 + t;
    int v = (i < N) ? deg[i] + 1 : 0;
    int x = v;
#pragma unroll
    for (int off = 1; off < 64; off <<= 1) {
        int u = __shfl_up(x, off);
        if (lane >= off) x += u;
    }
    if (lane == 63) ws[wid] = x;
    __syncthreads();
    int base = acc;
    for (int w = 0; w < wid; ++w) base += ws[w];
    int excl = base + x - v;
    if (i < N) { rowptr[i] = excl; cursor[i] = excl; }
    if (b == (int)gridDim.x - 1 && t == 0)
        rowptr[N] = acc + ws[0] + ws[1] + ws[2] + ws[3];
}

// ---- K5: fused per-node GATv2 + residual + LayerNorm. One wave per node.
// Settled structure (78.5 µs, 3.4 TB/s effective gather wall): depth-2 row pipeline,
// DPP row_ror reduce, register pin, __launch_bounds__(256,2).
// R11 ERRATA: int8 xl gather (halved bytes) gave NO net win -- agg is not simple
// HBM-byte-bound (xl is L3-resident either way); reverted to bf16 gather.
__global__ __launch_bounds__(256, 2) void agg_kernel(
    const bf16* __restrict__ xl, bf16* __restrict__ xr,
    const void* __restrict__ xv, const int* __restrict__ rowptr,
    const int* __restrict__ srcs, const float* __restrict__ smalls,
    int N, const int* __restrict__ flags) {
    int n = blockIdx.x * 4 + (threadIdx.x >> 6);
    if (n >= N) return;
    int lane = threadIdx.x & 63;
    int h = lane >> 4, cg = lane & 15;
    const float* att = smalls + 1024;
    const float* gat_bias = smalls + 1536;
    const float* ln_g = smalls + 1664;
    const float* ln_b = smalls + 1792;

    float att_f[8];
    {
        const float4* ap = (const float4*)(att + (size_t)h * 128 + cg * 8);
        float4 a0 = ap[0], a1 = ap[1];
        att_f[0] = a0.x; att_f[1] = a0.y; att_f[2] = a0.z; att_f[3] = a0.w;
        att_f[4] = a1.x; att_f[5] = a1.y; att_f[6] = a1.z; att_f[7] = a1.w;
    }
    float xr_f[8];
    uint4 xw = ((const uint4*)(xr + (size_t)n * 512))[lane];
    unpack8(xw, xr_f);

    float o[8];
#pragma unroll
    for (int j = 0; j < 8; ++j) o[j] = 0.f;
    float lsum = 0.f;

    int beg = rowptr[n], end = rowptr[n + 1];
    int last = end - 1;
    const uint4* xlu = (const uint4*)xl;
    int sA = srcs[beg];
    int sB = srcs[min(beg + 1, last)];
    uint4 lw = xlu[(size_t)sA * 64 + lane];
    for (int i = beg; i < end; ++i) {
        uint4 cur = lw;
        int snext = sB;
        sB = srcs[min(i + 2, last)];
        lw = xlu[(size_t)snext * 64 + lane];
        float v[8];
        unpack8(cur, v);
        // lrelu(z)*a summed == 0.6*(z.a) + 0.4*(|z|.a)
        float dotA = 0.f, dotB = 0.f;
#pragma unroll
        for (int j = 0; j < 8; ++j) {
            float z = v[j] + xr_f[j];
            dotA = fmaf(z, att_f[j], dotA);
            dotB = fmaf(fabsf(z), att_f[j], dotB);
        }
        float p = fmaf(0.4f, dotB, 0.6f * dotA);
        // all-lanes sum within the 16-lane head group (DPP rotation reduce)
        p = ror_add16<0x128>(p);  // row_ror:8
        p = ror_add16<0x124>(p);  // row_ror:4
        p = ror_add16<0x122>(p);  // row_ror:2
        p = ror_add16<0x121>(p);  // row_ror:1
        float w = __expf(fminf(p, 60.f));
        lsum += w;
#pragma unroll
        for (int j = 0; j < 8; ++j) o[j] = fmaf(w, v[j], o[j]);
        // Pin persistent state in arch VGPRs (emits nothing; defeats remat/AGPR-shuffle).
        asm volatile("" : "+v"(o[0]), "+v"(o[1]), "+v"(o[2]), "+v"(o[3]),
                          "+v"(o[4]), "+v"(o[5]), "+v"(o[6]), "+v"(o[7]),
                          "+v"(lsum),
                          "+v"(att_f[0]), "+v"(att_f[1]), "+v"(att_f[2]), "+v"(att_f[3]),
                          "+v"(att_f[4]), "+v"(att_f[5]), "+v"(att_f[6]), "+v"(att_f[7]),
                          "+v"(xr_f[0]), "+v"(xr_f[1]), "+v"(xr_f[2]), "+v"(xr_f[3]),
                          "+v"(xr_f[4]), "+v"(xr_f[5]), "+v"(xr_f[6]), "+v"(xr_f[7]));
    }
    float inv = 0.25f / lsum;
#pragma unroll
    for (int j = 0; j < 8; ++j) o[j] *= inv;
#pragma unroll
    for (int j = 0; j < 8; ++j) {
        o[j] += __shfl_xor(o[j], 16);
        o[j] += __shfl_xor(o[j], 32);
    }
    // residual x (std order): slot t of lane -> std channels bc+16c (+1 for t>=4)
    int bc = 64 * (cg >> 3) + 2 * (cg & 7);
    float xf[8];
    if (flags[0]) {
#pragma unroll
        for (int c = 0; c < 4; ++c) {
            unsigned d = *(const unsigned*)((const unsigned short*)xv + (size_t)n * 128 + bc + 16 * c);
            xf[c] = bits2f(d); xf[c + 4] = hi2f(d);
        }
    } else {
#pragma unroll
        for (int c = 0; c < 4; ++c) {
            float2 f = *(const float2*)((const float*)xv + (size_t)n * 128 + bc + 16 * c);
            xf[c] = f.x; xf[c + 4] = f.y;
        }
    }
    float gb[8];
    {
        const float4* gp = (const float4*)(gat_bias + cg * 8);
        float4 a0 = gp[0], a1 = gp[1];
        gb[0] = a0.x; gb[1] = a0.y; gb[2] = a0.z; gb[3] = a0.w;
        gb[4] = a1.x; gb[5] = a1.y; gb[6] = a1.z; gb[7] = a1.w;
    }
    float vl[8];
    float s1v = 0.f;
#pragma unroll
    for (int j = 0; j < 8; ++j) { vl[j] = xf[j] + o[j] + gb[j]; s1v += vl[j]; }
    s1v += __shfl_xor(s1v, 1); s1v += __shfl_xor(s1v, 2);
    s1v += __shfl_xor(s1v, 4); s1v += __shfl_xor(s1v, 8);
    float mu = s1v * (1.f / 128.f);
    float s2v = 0.f;
#pragma unroll
    for (int j = 0; j < 8; ++j) { float d = vl[j] - mu; s2v += d * d; }
    s2v += __shfl_xor(s2v, 1); s2v += __shfl_xor(s2v, 2);
    s2v += __shfl_xor(s2v, 4); s2v += __shfl_xor(s2v, 8);
    float rinv = rsqrtf(s2v * (1.f / 128.f) + LN_EPS);
    if (h == 0) {  // lanes 0..15: hn slot-bf16 -> bytes 0..255 of the xr row
        float g[8], bt[8];
        const float4* gp = (const float4*)(ln_g + cg * 8);
        float4 g0 = gp[0], g1 = gp[1];
        g[0] = g0.x; g[1] = g0.y; g[2] = g0.z; g[3] = g0.w;
        g[4] = g1.x; g[5] = g1.y; g[6] = g1.z; g[7] = g1.w;
        const float4* bp = (const float4*)(ln_b + cg * 8);
        float4 b0 = bp[0], b1v = bp[1];
        bt[0] = b0.x; bt[1] = b0.y; bt[2] = b0.z; bt[3] = b0.w;
        bt[4] = b1v.x; bt[5] = b1v.y; bt[6] = b1v.z; bt[7] = b1v.w;
        float hnv[8];
#pragma unroll
        for (int j = 0; j < 8; ++j) hnv[j] = (vl[j] - mu) * rinv * g[j] + bt[j];
        char* rowp = (char*)xr + (size_t)n * 1024;
        uint4 pk;
        pk.x = (unsigned)f2b_bits(hnv[0]) | ((unsigned)f2b_bits(hnv[1]) << 16);
        pk.y = (unsigned)f2b_bits(hnv[2]) | ((unsigned)f2b_bits(hnv[3]) << 16);
        pk.z = (unsigned)f2b_bits(hnv[4]) | ((unsigned)f2b_bits(hnv[5]) << 16);
        pk.w = (unsigned)f2b_bits(hnv[6]) | ((unsigned)f2b_bits(hnv[7]) << 16);
        *(uint4*)(rowp + cg * 16) = pk;
    }
}

// ---- K6: fused FFN: mid = lrelu(hn@W1+b1) in LDS; out = mid@W2 + hn + b2
// A staged via LDS (coalesced), W1t/W2x fragment-ordered (1 KB contiguous per
// B-load). Epilogue stages C in the dead LDS buffer, then writes flat-contiguous.
__global__ __launch_bounds__(256) void ffn_fused_kernel(
    const char* __restrict__ hnrows, const unsigned short* __restrict__ W1t,
    const unsigned short* __restrict__ W2x, const float* __restrict__ smalls,
    void* __restrict__ outv, int N, const int* __restrict__ flags) {
    __shared__ __align__(16) char lds[64 * 528];   // A-stage [64][272] -> mid [64][528] -> C [64][132 f32]
    const float* b1 = smalls + 1920;
    const float* b2v = smalls + 2176;
    int tt = (int)threadIdx.x;
    int wid = threadIdx.x >> 6, lane = threadIdx.x & 63;
    int quad = lane >> 4, l16 = lane & 15;
    int m0 = blockIdx.x * 64;

    // stage A (hn slot-bf16 rows, 256 B each) into LDS, coalesced
#pragma unroll
    for (int s = 0; s < 4; ++s) {
        int row = s * 16 + (tt >> 4);
        int gr = m0 + row; gr = (gr < N) ? gr : N - 1;
        uint4 v = *(const uint4*)(hnrows + (size_t)gr * 1024 + (tt & 15) * 16);
        *(uint4*)(lds + row * 272 + (tt & 15) * 16) = v;
    }
    __syncthreads();
    short8 A[4][4];  // hn slot-bf16, kept for the residual K-extension
#pragma unroll
    for (int rf = 0; rf < 4; ++rf)
#pragma unroll
        for (int k4 = 0; k4 < 4; ++k4)
            A[rf][k4] = ld8b(lds + (rf * 16 + l16) * 272 + (k4 * 32 + quad * 8) * 2);
    __syncthreads();   // A in regs; lds free for mid

    // ---- phase 1: mid cols n0..n0+63, all 64 rows ----
    {
        int n0 = wid * 64;
        f32x4 acc[4][4];
#pragma unroll
        for (int rf = 0; rf < 4; ++rf)
#pragma unroll
            for (int c = 0; c < 4; ++c) acc[rf][c] = (f32x4){0.f, 0.f, 0.f, 0.f};
#pragma unroll
        for (int k4 = 0; k4 < 4; ++k4) {
            short8 b[4];
#pragma unroll
            for (int c = 0; c < 4; ++c)
                b[c] = ld8b((const char*)(W1t + (((size_t)(wid * 4 + c) * 4 + k4) * 64 + lane) * 8));
#pragma unroll
            for (int rf = 0; rf < 4; ++rf)
#pragma unroll
                for (int c = 0; c < 4; ++c)
                    acc[rf][c] = __builtin_amdgcn_mfma_f32_16x16x32_bf16(A[rf][k4], b[c], acc[rf][c], 0, 0, 0);
        }
        float bv[4];
#pragma unroll
        for (int c = 0; c < 4; ++c) bv[c] = b1[n0 + c * 16 + l16];
#pragma unroll
        for (int rf = 0; rf < 4; ++rf) {
#pragma unroll
            for (int j = 0; j < 4; ++j) {
                int lrow = rf * 16 + quad * 4 + j;
                uint2 pk;
                pk.x = (unsigned)f2b_bits(lrelu(acc[rf][0][j] + bv[0])) |
                       ((unsigned)f2b_bits(lrelu(acc[rf][1][j] + bv[1])) << 16);
                pk.y = (unsigned)f2b_bits(lrelu(acc[rf][2][j] + bv[2])) |
                       ((unsigned)f2b_bits(lrelu(acc[rf][3][j] + bv[3])) << 16);
                *(uint2*)(lds + lrow * 528 + (n0 + 4 * l16) * 2) = pk;
            }
        }
    }
    __syncthreads();
    // ---- phase 2: out rows rh*32..+31, cols nh*64..+63; K=256 (LDS) + 128 (regs) ----
    int rh = wid >> 1, nh = wid & 1;
    int n0b = nh * 64;
    f32x4 a2[2][4];
#pragma unroll
    for (int rfl = 0; rfl < 2; ++rfl)
#pragma unroll
        for (int c = 0; c < 4; ++c) a2[rfl][c] = (f32x4){0.f, 0.f, 0.f, 0.f};
#pragma unroll
    for (int kk = 0; kk < 256; kk += 32) {
        int k4 = kk >> 5;
        short8 am[2], b[4];
#pragma unroll
        for (int rfl = 0; rfl < 2; ++rfl)
            am[rfl] = ld8b(lds + (rh * 32 + rfl * 16 + l16) * 528 + (kk + quad * 8) * 2);
#pragma unroll
        for (int c = 0; c < 4; ++c)
            b[c] = ld8b((const char*)(W2x + (((size_t)(nh * 4 + c) * 12 + k4) * 64 + lane) * 8));
#pragma unroll
        for (int rfl = 0; rfl < 2; ++rfl)
#pragma unroll
            for (int c = 0; c < 4; ++c)
                a2[rfl][c] = __builtin_amdgcn_mfma_f32_16x16x32_bf16(am[rfl], b[c], a2[rfl][c], 0, 0, 0);
    }
#pragma unroll
    for (int k4 = 0; k4 < 4; ++k4) {  // residual: hn slot regs x perm-identity (K blocks 8..11)
        short8 b[4];
#pragma unroll
        for (int c = 0; c < 4; ++c)
            b[c] = ld8b((const char*)(W2x + (((size_t)(nh * 4 + c) * 12 + 8 + k4) * 64 + lane) * 8));
#pragma unroll
        for (int rfl = 0; rfl < 2; ++rfl)
#pragma unroll
            for (int c = 0; c < 4; ++c)
                a2[rfl][c] = __builtin_amdgcn_mfma_f32_16x16x32_bf16(A[rh * 2 + rfl][k4], b[c], a2[rfl][c], 0, 0, 0);
    }
    // ---- epilogue: stage C into LDS (mid dead after kk loop), write coalesced ----
    __syncthreads();   // all waves done reading mid
#pragma unroll
    for (int c = 0; c < 4; ++c) {
        int col = n0b + c * 16 + l16;
        float bv = b2v[col];
#pragma unroll
        for (int rfl = 0; rfl < 2; ++rfl) {
#pragma unroll
            for (int j = 0; j < 4; ++j) {
                int lrow = rh * 32 + rfl * 16 + quad * 4 + j;
                *(float*)(lds + lrow * 528 + col * 4) = a2[rfl][c][j] + bv;
            }
        }
    }
    __syncthreads();
    int isb = flags[0];
    int t = (int)threadIdx.x;
    if (isb) {
        // flat bf16 tile: 64 rows x 128 = 8192 vals; 4 steps x 256 threads x 8 vals.
#pragma unroll
        for (int k = 0; k < 4; ++k) {
            int f = t * 8 + k * 2048;          // flat val index
            int lrow = f >> 7, col = f & 127;
            int row = m0 + lrow;
            if (row < N) {
                const float* src = (const float*)(lds + lrow * 528) + col;
                uint4 pk;
                pk.x = (unsigned)f2b_bits(src[0]) | ((unsigned)f2b_bits(src[1]) << 16);
                pk.y = (unsigned)f2b_bits(src[2]) | ((unsigned)f2b_bits(src[3]) << 16);
                pk.z = (unsigned)f2b_bits(src[4]) | ((unsigned)f2b_bits(src[5]) << 16);
                pk.w = (unsigned)f2b_bits(src[6]) | ((unsigned)f2b_bits(src[7]) << 16);
                *(uint4*)((unsigned short*)outv + (size_t)row * 128 + col) = pk;
            }
        }
    } else {
        // flat f32 tile: 8 steps x 256 threads x 4 vals.
#pragma unroll
        for (int k = 0; k < 8; ++k) {
            int f = t * 4 + k * 1024;
            int lrow = f >> 7, col = f & 127;
            int row = m0 + lrow;
            if (row < N) {
                const float* src = (const float*)(lds + lrow * 528) + col;
                float4 v = *(const float4*)src;
                *(float4*)((float*)outv + (size_t)row * 128 + col) = v;
            }
        }
    }
}

extern "C" void kernel_launch(void* const* d_in, const int* in_sizes, int n_in,
                              void* d_out, int out_size, void* d_ws, size_t ws_size,
                              hipStream_t stream) {
    const void* x = d_in[0];
    const int* ei = (const int*)d_in[1];

    int N = in_sizes[0] / 128;
    int E = in_sizes[1] / 2;
    int ET = E + N;
    int nb = (N + 255) / 256;

    // ---- workspace layout (~105 MB)
    char* base = (char*)d_ws;
    int* flags = (int*)base;
    size_t off = 256;
    float* smalls = (float*)(base + off);               off += 2304 * 4;
    off = (off + 255) & ~(size_t)255;
    unsigned short* Wlt = (unsigned short*)(base + off); off += 512 * 128 * 2;
    unsigned short* Wrt = (unsigned short*)(base + off); off += 512 * 128 * 2;
    unsigned short* W1t = (unsigned short*)(base + off); off += 256 * 128 * 2;
    unsigned short* W2x = (unsigned short*)(base + off); off += 128 * 384 * 2;
    off = (off + 1023) & ~(size_t)1023;
    bf16* xl = (bf16*)(base + off);   off += (size_t)N * 512 * 2;
    bf16* xr = (bf16*)(base + off);   off += (size_t)N * 512 * 2;  // rows reused: hn slot bf16 (256 B)
    int* srcs = (int*)(base + off);   off += (size_t)ET * 4;
    int* rowptr = (int*)(base + off); off += (size_t)(N + 1) * 4;
    int* deg = (int*)(base + off);    off += (size_t)N * 4;
    int* cursor = (int*)(base + off); off += (size_t)N * 4;
    int* part = (int*)(base + off);   off += (size_t)nb * 4;
    const char* hnrows = (const char*)xr;

    // deg zero-init (hist folded into prep seg 4)
    hipMemsetAsync(deg, 0, (size_t)N * 4, stream);

    detect_kernel<<<1, 64, 0, stream>>>((const unsigned*)x, ei, flags, E);

    PrepArgs pa;
    pa.Wl = d_in[2]; pa.Wr = d_in[4]; pa.W1 = d_in[10]; pa.W2 = d_in[12];
    pa.ssrc[0] = d_in[3];  pa.ssrc[1] = d_in[5];  pa.ssrc[2] = d_in[6];
    pa.ssrc[3] = d_in[7];  pa.ssrc[4] = d_in[8];  pa.ssrc[5] = d_in[9];
    pa.ssrc[6] = d_in[11]; pa.ssrc[7] = d_in[13];
    pa.ei = ei;
    pa.Wlt = Wlt; pa.Wrt = Wrt; pa.W1t = W1t; pa.W2x = W2x;
    pa.smalls = smalls; pa.deg = deg; pa.N = N; pa.E = E;
    int px = (E > 65536 ? E : 65536);
    prep_kernel<<<dim3((px + 255) / 256, 6), 256, 0, stream>>>(pa, flags);

    // CSR scans first (depend only on prep's hist) ...
    scanA_kernel<<<nb, 256, 0, stream>>>(deg, part, N);
    scanC_kernel<<<nb, 256, 0, stream>>>(deg, part, rowptr, cursor, N);

    // ... then proj and scatter share ONE dispatch (independent chains join here)
    int g64 = (N + 63) / 64;
    int scb = (ET + 255) / 256;
    proj_scatter_kernel<<<g64 + scb, 256, 0, stream>>>(
        x, Wlt, Wrt, smalls, (unsigned short*)xl, (unsigned short*)xr,
        ei, cursor, srcs, N, E, ET, g64, flags);

    agg_kernel<<<(N + 3) / 4, 256, 0, stream>>>(xl, xr, x, rowptr, srcs, smalls, N, flags);

    ffn_fused_kernel<<<g64, 256, 0, stream>>>(hnrows, W1t, W2x, smalls, d_out, N, flags);
}